// Round 15
// baseline (679.091 us; speedup 1.0000x reference)
//
#include <hip/hip_runtime.h>
#include <stdint.h>
#include <stddef.h>

#define S_LEN 2048
#define BATCH 2
#define NHEADS 32
#define NKV 8
#define HD 128
#define HIDDEN 4096
#define T_TOK (BATCH * S_LEN)
// fused QKV activation row: [0,4096)=Q heads, [4096,5120)=K, [5120,6144)=V
#define QKV_W 6144

typedef unsigned short u16;
typedef __attribute__((ext_vector_type(4))) float f32x4;
typedef __attribute__((ext_vector_type(16))) float f32x16;
typedef __attribute__((ext_vector_type(8))) short s16x8;
typedef __attribute__((ext_vector_type(4))) unsigned short u16x4;
typedef __attribute__((ext_vector_type(4))) unsigned int u32x4;

__device__ __forceinline__ u16 f2bf(float f) {
  unsigned int u = __builtin_bit_cast(unsigned int, f);
  unsigned int r = (u + 0x7FFFu + ((u >> 16) & 1u)) >> 16;
  return (u16)r;
}
__device__ __forceinline__ float bf2f(u16 h) {
  return __builtin_bit_cast(float, ((unsigned int)h) << 16);
}

__device__ __forceinline__ void gload16(const void* g, void* l) {
  __builtin_amdgcn_global_load_lds((__attribute__((address_space(1))) void*)g,
                                   (__attribute__((address_space(3))) void*)l,
                                   16, 0, 0);
}

__device__ __forceinline__ unsigned cvtpk(float a, float b) {
  unsigned r;
  asm("v_cvt_pk_bf16_f32 %0, %1, %2" : "=v"(r) : "v"(a), "v"(b));
  return r;
}
__device__ __forceinline__ void lohi_dup(unsigned W, unsigned& lo, unsigned& hi) {
  unsigned a = W, b = W;
  asm volatile("v_permlane32_swap_b32 %0, %1" : "+v"(a), "+v"(b));
  lo = a; hi = b;
}

// ---------------- convert f32 -> bf16 (8 elems / thread) ----------------
__global__ __launch_bounds__(256) void k_convert(const float* __restrict__ in,
                                                 u16* __restrict__ out, int n8) {
  int i = blockIdx.x * 256 + threadIdx.x;
  if (i >= n8) return;
  float4 a = ((const float4*)in)[i * 2];
  float4 b = ((const float4*)in)[i * 2 + 1];
  u16x4 lo = {f2bf(a.x), f2bf(a.y), f2bf(a.z), f2bf(a.w)};
  u16x4 hi = {f2bf(b.x), f2bf(b.y), f2bf(b.z), f2bf(b.w)};
  ((u16x4*)out)[i * 2] = lo;
  ((u16x4*)out)[i * 2 + 1] = hi;
}

// ------------- transpose-convert W [K][N] f32 -> Wt [N][K] bf16 ----------
__global__ __launch_bounds__(256) void k_transpose_w(const float* __restrict__ W,
                                                     u16* __restrict__ Wt, int K,
                                                     int N, int outRowOff,
                                                     int outStride) {
  __shared__ float tl[32][33];
  int k0 = blockIdx.x * 32, n0 = blockIdx.y * 32;
  int t = threadIdx.x;
  int r = t >> 3, c4 = (t & 7) * 4;
  float4 v = *(const float4*)&W[(size_t)(k0 + r) * N + n0 + c4];
  tl[r][c4] = v.x; tl[r][c4 + 1] = v.y; tl[r][c4 + 2] = v.z; tl[r][c4 + 3] = v.w;
  __syncthreads();
  u16x4 o = {f2bf(tl[c4][r]), f2bf(tl[c4 + 1][r]), f2bf(tl[c4 + 2][r]),
             f2bf(tl[c4 + 3][r])};
  *(u16x4*)&Wt[(size_t)(outRowOff + n0 + r) * outStride + k0 + c4] = o;
}

// ---------------- RoPE cos/sin table: tab[s][0:64]=cos, [64:128]=sin -----
__global__ __launch_bounds__(256) void k_rope_tab(const int* __restrict__ pos,
                                                  float* __restrict__ tab) {
  int i = blockIdx.x * 256 + threadIdx.x;  // S*64
  int s = i >> 6, l = i & 63;
  float p = (float)pos[s];
  float ang = p * expf(-(float)l * 0.14391156516342163f);
  tab[s * 128 + l] = cosf(ang);
  tab[s * 128 + 64 + l] = sinf(ang);
}

// ===== 256x256xBK64 8-wave 8-PHASE GEMM with register-prefetch pipeline ====
// R14 post-mortem: per-phase lgkmcnt(0) drains exposed full ds_read latency
// (8x/iter) and a wave's DS reads never overlap its own MFMAs (MfmaUtil 35%).
// This version: NO explicit lgkm waits (reads are plain loads; compiler
// inserts exact counted lgkm waits before consuming MFMAs). Fragment reads
// issue ONE PHASE EARLY so their latency hides under the previous quad's
// MFMA cluster. Buffer-switch phases (P0, P4) keep in-phase reads: their
// buffer is only certified landed by the preceding VM(4)+barrier.
// READ SCHEDULE (per iter j; quads Q0..Q3 on buf0, Q4..Q7 on buf1):
//   P0: rd af(buf0,mh0)+bf0(buf0,nh0) [in-phase] + bf1(buf0,nh1) [prefetch]
//   P1: rd af2(buf0,mh1) [prefetch];  P2,P3: no reads
//   P4: rd af(buf1,mh0)+bf0(buf1,nh0) [in-phase] + bf1(buf1,nh1) [prefetch]
//   P5: rd af2(buf1,mh1) [prefetch];  P6,P7: no reads
// STAGE/VMCNT LEDGER (identical to R14): p0,p1 stg (2j+1).A->buf1;
// p2,p3 stg (2j+2).B->buf0; p4,p5 stg (2j+2).A->buf0; p6,p7 stg (2j+3).B->
// buf1. End-p3 VM(4) (newest 4 = p2,p3) -> tile 2j+1 landed; final iter
// VM(0) there (counted wait would no-op, R8 bug class). End-p7 VM(4) ->
// tile 2j+2 landed. Every VM is followed by s_barrier.
// PREFETCH-vs-STAGE HAZARDS (each prefetched read retires via the compiler's
// auto-wait before its consuming quad, which precedes the barrier after
// which its region is next staged):
//   bf1(buf0) rd@P0, used Q1@P1 (< B_p1); Bs[0] staged @P2  -> 1 barrier gap
//   af2(buf0) rd@P1, used Q2@P2 (< B_p2); As[0] staged @P4  -> 2 barriers
//   bf1(buf1) rd@P4, used Q5@P5 (< B_p5); Bs[1] staged @P6  -> 1 barrier
//   af2(buf1) rd@P5, used Q6@P6 (< B_p6); As[1] staged @next-P0 -> 2 barriers
// Intra-phase: every stage target is disjoint from every read region of the
// same phase (different array or different buffer) -- checked all 8 phases.
template <typename OutT>
__global__ __launch_bounds__(512) void k_gemm8p(const u16* __restrict__ A,
                                                const u16* __restrict__ Bt,
                                                OutT* __restrict__ C,
                                                int N, int K) {
  __shared__ u16 As[2][16384];  // [buf][256 rows][64 k], xor-swizzled rows
  __shared__ u16 Bs[2][16384];
  int nbn = N >> 8;
  int nwg = gridDim.x;
  int orig = blockIdx.x;
  int q8 = nwg >> 3, r8 = nwg & 7;
  int xcd = orig & 7, sub = orig >> 3;
  int wgid = (xcd < r8 ? xcd * (q8 + 1) : r8 * (q8 + 1) + (xcd - r8) * q8) + sub;
  int bm = wgid / nbn, bn = wgid % nbn;
  int tid = threadIdx.x, wid = tid >> 6, lane = tid & 63;
  int wm = wid >> 2, wn = wid & 3;  // 2M x 4N waves; wave tile 128x64
  int g = lane >> 4, c = lane & 15;
  int l3 = lane >> 3, l7 = lane & 7;
  int swz = c & 7;
  int xunit = (l7 ^ l3) * 8;  // inverse-swizzled 16B unit for staging

  f32x4 acc[8][4];
#pragma unroll
  for (int m = 0; m < 8; m++)
#pragma unroll
    for (int n = 0; n < 4; n++) acc[m][n] = (f32x4){0.f, 0.f, 0.f, 0.f};

  const u16* aBase = A + (size_t)(bm * 256 + wid * 16 + l3) * K + xunit;
  const u16* bBase = Bt + (size_t)(bn * 256 + wid * 16 + l3) * K + xunit;

  auto stgA = [&](int buf, int h, size_t koff) {
    gload16(aBase + (size_t)(h * 128) * K + koff,
            &As[buf][(h * 128 + wid * 16) * 64]);
    gload16(aBase + (size_t)(h * 128 + 8) * K + koff,
            &As[buf][(h * 128 + wid * 16 + 8) * 64]);
  };
  auto stgB = [&](int buf, int h, size_t koff) {
    gload16(bBase + (size_t)(h * 128) * K + koff,
            &Bs[buf][(h * 128 + wid * 16) * 64]);
    gload16(bBase + (size_t)(h * 128 + 8) * K + koff,
            &Bs[buf][(h * 128 + wid * 16 + 8) * 64]);
  };

  s16x8 af[4][2], af2[4][2], bf0[2][2], bf1[2][2];
  auto rdA = [&](s16x8 (&d)[4][2], int buf, int mh) {
#pragma unroll
    for (int mi = 0; mi < 4; mi++)
#pragma unroll
      for (int ks = 0; ks < 2; ks++)
        d[mi][ks] = *(const s16x8*)&As[buf][(wm * 128 + mh * 64 + mi * 16 + c) * 64 +
                                           (((ks * 4 + g) ^ swz) * 8)];
  };
  auto rdB = [&](s16x8 (&d)[2][2], int buf, int nh) {
#pragma unroll
    for (int nj = 0; nj < 2; nj++)
#pragma unroll
      for (int ks = 0; ks < 2; ks++)
        d[nj][ks] = *(const s16x8*)&Bs[buf][(wn * 64 + nh * 32 + nj * 16 + c) * 64 +
                                           (((ks * 4 + g) ^ swz) * 8)];
  };
  auto quad = [&](s16x8 (&a)[4][2], s16x8 (&bf)[2][2], int mh, int nh) {
    __builtin_amdgcn_s_setprio(1);
#pragma unroll
    for (int mi = 0; mi < 4; mi++)
#pragma unroll
      for (int nj = 0; nj < 2; nj++)
#pragma unroll
        for (int ks = 0; ks < 2; ks++)
          acc[mh * 4 + mi][nh * 2 + nj] = __builtin_amdgcn_mfma_f32_16x16x32_bf16(
              a[mi][ks], bf[nj][ks], acc[mh * 4 + mi][nh * 2 + nj], 0, 0, 0);
    __builtin_amdgcn_s_setprio(0);
  };
#define BAR()                          \
  do {                                 \
    __builtin_amdgcn_s_barrier();      \
    __builtin_amdgcn_sched_barrier(0); \
  } while (0)
#define VM(n) asm volatile("s_waitcnt vmcnt(" #n ")" ::: "memory")

  int nt2 = K >> 7;  // iterations; 2 K-tiles each (K=4096 -> 32)
  // prologue: t0 -> buf0 (B0,B1,A0,A1), t1.B -> buf1. 12 ops; vmcnt(4)
  // leaves only t1.B outstanding -> t0 complete.
  stgB(0, 0, 0); stgB(0, 1, 0);
  stgA(0, 0, 0); stgA(0, 1, 0);
  stgB(1, 0, 64); stgB(1, 1, 64);
  VM(4);
  BAR();

  for (int j = 0; j < nt2; j++) {
    size_t k1 = (size_t)(2 * j + 1) << 6;
    size_t k2 = (size_t)(2 * j + 2) << 6;
    size_t k3 = (size_t)(2 * j + 3) << 6;
    bool st = (j + 1 < nt2);  // stage tiles 2j+2, 2j+3?
    // ---- P0: rd Q0 frags + prefetch bf1; stage (2j+1).A0 -> buf1 ----
    rdA(af, 0, 0); rdB(bf0, 0, 0); rdB(bf1, 0, 1);
    stgA(1, 0, k1);
    quad(af, bf0, 0, 0);
    BAR();
    // ---- P1: prefetch af2 (buf0 mh1); stage (2j+1).A1 -> buf1 ----
    rdA(af2, 0, 1);
    stgA(1, 1, k1);
    quad(af, bf1, 0, 1);
    BAR();
    // ---- P2: stage (2j+2).B0 -> buf0 ----
    if (st) stgB(0, 0, k2);
    quad(af2, bf0, 1, 0);
    BAR();
    // ---- P3: stage (2j+2).B1 -> buf0; WAIT(tile 2j+1) ----
    if (st) stgB(0, 1, k2);
    quad(af2, bf1, 1, 1);
    if (st) { VM(4); } else { VM(0); }
    BAR();
    // ---- P4: rd Q4 frags + prefetch bf1 (buf1); stage (2j+2).A0 -> buf0 --
    rdA(af, 1, 0); rdB(bf0, 1, 0); rdB(bf1, 1, 1);
    if (st) stgA(0, 0, k2);
    quad(af, bf0, 0, 0);
    BAR();
    // ---- P5: prefetch af2 (buf1 mh1); stage (2j+2).A1 -> buf0 ----
    rdA(af2, 1, 1);
    if (st) stgA(0, 1, k2);
    quad(af, bf1, 0, 1);
    BAR();
    // ---- P6: stage (2j+3).B0 -> buf1 ----
    if (st) stgB(1, 0, k3);
    quad(af2, bf0, 1, 0);
    BAR();
    // ---- P7: stage (2j+3).B1 -> buf1; WAIT(tile 2j+2) ----
    if (st) stgB(1, 1, k3);
    quad(af2, bf1, 1, 1);
    if (st) { VM(4); }
    BAR();
  }
#undef BAR
#undef VM

  // epilogue
#pragma unroll
  for (int m = 0; m < 8; m++)
#pragma unroll
    for (int n = 0; n < 4; n++) {
      size_t row = (size_t)bm * 256 + wm * 128 + m * 16 + g * 4;
      size_t col = (size_t)bn * 256 + wn * 64 + n * 16 + c;
#pragma unroll
      for (int r = 0; r < 4; r++) {
        float v = acc[m][n][r];
        if constexpr (sizeof(OutT) == 2)
          C[(row + r) * N + col] = (OutT)f2bf(v);
        else
          C[(row + r) * N + col] = (OutT)v;
      }
    }
}

// ------------- fused per-head RMSNorm + RoPE (in-place, bf16) ------------
__global__ __launch_bounds__(256) void k_rmsrope(u16* __restrict__ QK,
                                                 const float* __restrict__ w,
                                                 const float* __restrict__ tab,
                                                 int H, int rowStride) {
  int row = blockIdx.x * 4 + (threadIdx.x >> 6);
  int lane = threadIdx.x & 63;
  int t = row / H, h = row - t * H;
  int s = t & (S_LEN - 1);
  u16* p = QK + (size_t)t * rowStride + h * HD;
  float x1 = bf2f(p[lane]), x2 = bf2f(p[lane + 64]);
  float ss = x1 * x1 + x2 * x2;
#pragma unroll
  for (int o = 32; o >= 1; o >>= 1) ss += __shfl_xor(ss, o);
  float inv = rsqrtf(ss * (1.0f / 128.0f) + 1e-6f);
  float y1 = x1 * inv * w[lane], y2 = x2 * inv * w[lane + 64];
  float cs = tab[s * 128 + lane], sn = tab[s * 128 + 64 + lane];
  p[lane] = f2bf(y1 * cs - y2 * sn);
  p[lane + 64] = f2bf(y2 * cs + y1 * sn);
}

// ---- transpose V: QKV[t][5120 + kh*128 + d] -> Vt[bkh*128+d][s] ----
__global__ __launch_bounds__(256) void k_transpose_v(const u16* __restrict__ QKV,
                                                     u16* __restrict__ Vt) {
  __shared__ u16 tl[32][40];
  int bkh = blockIdx.x;
  int s0 = blockIdx.y * 32, d0 = blockIdx.z * 32;
  int b = bkh >> 3, kh = bkh & 7;
  int t = threadIdx.x, r = t >> 3, c4 = (t & 7) * 4;
  const u16* src =
      QKV + (size_t)(b * S_LEN + s0 + r) * QKV_W + 5120 + kh * HD + d0 + c4;
  u16x4 v = *(const u16x4*)src;
  tl[r][c4] = v[0]; tl[r][c4 + 1] = v[1]; tl[r][c4 + 2] = v[2]; tl[r][c4 + 3] = v[3];
  __syncthreads();
  u16x4 o = {tl[c4][r], tl[c4 + 1][r], tl[c4 + 2][r], tl[c4 + 3][r]};
  *(u16x4*)&Vt[(size_t)(bkh * HD + d0 + r) * S_LEN + s0 + c4] = o;
}

// --------------------------- causal GQA attention ------------------------
// R7/R11-PROVEN structure (do not touch sync): 512 blocks, XCD-grouped;
// each block = one (b,h) processing q-tile PAIR {p, 15-p}; K,V double-
// buffered in 64 KiB LDS; ONE __syncthreads per chunk. Log2-domain softmax,
// T12 repack, T13 defer-max, T5 setprio.
__global__ __launch_bounds__(256) void k_attn(const u16* __restrict__ QKV,
                                              const u16* __restrict__ Vt,
                                              u16* __restrict__ Oact) {
  __shared__ u16 Ks[2][64 * 128];
  __shared__ u16 Vs[2][128 * 64];
  int bid = blockIdx.x;
  int xcd = bid & 7, slot = bid >> 3;
  int grp = xcd * 2 + (slot >> 5);  // 16 groups = b*8 + kh
  int b = grp >> 3, kh = grp & 7;
  int s32 = slot & 31;
  int pr = s32 >> 2;
  int h = kh * 4 + (s32 & 3);
  int w = threadIdx.x >> 6, lane = threadIdx.x & 63;
  int q31 = lane & 31, hh = lane >> 5;
  const float qscale = 0.12751740810f;  // 1/sqrt(128) * log2(e)

  const char* Kg = (const char*)(QKV + (size_t)b * S_LEN * QKV_W + 4096 + kh * HD);
  const char* Vg = (const char*)(Vt + (size_t)(b * 8 + kh) * HD * S_LEN);

#pragma unroll 1
  for (int half = 0; half < 2; half++) {
    __syncthreads();  // half-boundary safety: all prior LDS reads retired
    int qt = half ? 15 - pr : pr;
    int qw0 = qt * 128 + w * 32;

    s16x8 qf[8];
    const u16* Qp = QKV + (size_t)(b * S_LEN + qw0 + q31) * QKV_W + h * HD + hh * 8;
#pragma unroll
    for (int dc = 0; dc < 8; dc++) {
      s16x8 raw = *(const s16x8*)(Qp + dc * 16);
#pragma unroll
      for (int e = 0; e < 8; e++)
        qf[dc][e] = (short)f2bf(bf2f((u16)raw[e]) * qscale);
    }

    f32x16 o[4];
#pragma unroll
    for (int d = 0; d < 4; d++)
#pragma unroll
      for (int r = 0; r < 16; r++) o[d][r] = 0.f;
    float m = -3.0e38f, l = 0.f;

    int nch = 2 * qt + 2;

    {
      char* KsB = (char*)Ks[0];
      char* VsB = (char*)Vs[0];
#pragma unroll
      for (int j = 0; j < 4; j++) {
        int ins = w * 4 + j;
        int row = ins * 4 + (lane >> 4);
        int bc = ((lane & 15) * 16) ^ ((row & 7) << 4);
        gload16(Kg + (size_t)row * 12288 + bc, KsB + ins * 1024);
      }
#pragma unroll
      for (int j = 0; j < 4; j++) {
        int ins = w * 4 + j;
        int row = ins * 8 + (lane >> 3);
        int bc = ((lane & 7) * 16) ^ ((row & 7) << 4);
        gload16(Vg + (size_t)row * 4096 + bc, VsB + ins * 1024);
      }
    }

    int cur = 0;
    for (int ch = 0; ch < nch; ch++) {
      int kb = ch * 64;
      __syncthreads();
      if (ch + 1 < nch) {
        char* KsB = (char*)Ks[cur ^ 1];
        char* VsB = (char*)Vs[cur ^ 1];
        int kb2 = kb + 64;
#pragma unroll
        for (int j = 0; j < 4; j++) {
          int ins = w * 4 + j;
          int row = ins * 4 + (lane >> 4);
          int bc = ((lane & 15) * 16) ^ ((row & 7) << 4);
          gload16(Kg + (size_t)(kb2 + row) * 12288 + bc, KsB + ins * 1024);
        }
#pragma unroll
        for (int j = 0; j < 4; j++) {
          int ins = w * 4 + j;
          int row = ins * 8 + (lane >> 3);
          int bc = ((lane & 7) * 16) ^ ((row & 7) << 4);
          gload16(Vg + (size_t)row * 4096 + (size_t)kb2 * 2 + bc, VsB + ins * 1024);
        }
      }
      if (kb <= qw0 + 31) {
        char* KsB = (char*)Ks[cur];
        char* VsB = (char*)Vs[cur];
        f32x16 sA, sB;
#pragma unroll
        for (int r = 0; r < 16; r++) { sA[r] = 0.f; sB[r] = 0.f; }
        int sw = (q31 & 7) << 4;
        __builtin_amdgcn_s_setprio(1);
#pragma unroll
        for (int dc = 0; dc < 8; dc++) {
          s16x8 kfA = *(const s16x8*)(KsB + q31 * 256 + ((dc * 32 + hh * 16) ^ sw));
          s16x8 kfB = *(const s16x8*)(KsB + (32 + q31) * 256 + ((dc * 32 + hh * 16) ^ sw));
          sA = __builtin_amdgcn_mfma_f32_32x32x16_bf16(kfA, qf[dc], sA, 0, 0, 0);
          sB = __builtin_amdgcn_mfma_f32_32x32x16_bf16(kfB, qf[dc], sB, 0, 0, 0);
        }
        __builtin_amdgcn_s_setprio(0);
        if (kb + 63 > qw0) {
          int qa = qw0 + q31;
#pragma unroll
          for (int r = 0; r < 16; r++) {
            int krow = (r & 3) + 8 * (r >> 2) + 4 * hh;
            if (kb + krow > qa) sA[r] = -1e30f;
            if (kb + 32 + krow > qa) sB[r] = -1e30f;
          }
        }
        float mx = -3.0e38f;
#pragma unroll
        for (int r = 0; r < 16; r++) mx = fmaxf(mx, fmaxf(sA[r], sB[r]));
        mx = fmaxf(mx, __shfl_xor(mx, 32));
        if (!__all(mx - m <= 11.5f)) {
          float mnew = fmaxf(m, mx);
          float corr = __builtin_amdgcn_exp2f(m - mnew);
          l *= corr;
#pragma unroll
          for (int d = 0; d < 4; d++)
#pragma unroll
            for (int r = 0; r < 16; r++) o[d][r] *= corr;
          m = mnew;
        }
        float rs = 0.f;
#pragma unroll
        for (int r = 0; r < 16; r++) {
          sA[r] = __builtin_amdgcn_exp2f(sA[r] - m); rs += sA[r];
          sB[r] = __builtin_amdgcn_exp2f(sB[r] - m); rs += sB[r];
        }
        rs += __shfl_xor(rs, 32);
        l += rs;
#pragma unroll
        for (int st = 0; st < 2; st++) {
          unsigned Aw[8], Bw[8];
#pragma unroll
          for (int j = 0; j < 8; j++) {
            float p0 = st ? sB[2 * j] : sA[2 * j];
            float p1 = st ? sB[2 * j + 1] : sA[2 * j + 1];
            lohi_dup(cvtpk(p0, p1), Aw[j], Bw[j]);
          }
#pragma unroll
          for (int kc2 = 0; kc2 < 2; kc2++) {
            u32x4 wv;
            wv.x = hh ? Aw[kc2 * 4 + 2] : Aw[kc2 * 4 + 0];
            wv.y = hh ? Aw[kc2 * 4 + 3] : Aw[kc2 * 4 + 1];
            wv.z = hh ? Bw[kc2 * 4 + 2] : Bw[kc2 * 4 + 0];
            wv.w = hh ? Bw[kc2 * 4 + 3] : Bw[kc2 * 4 + 1];
            s16x8 pf = __builtin_bit_cast(s16x8, wv);
            int kc = st * 2 + kc2;
            __builtin_amdgcn_s_setprio(1);
#pragma unroll
            for (int d = 0; d < 4; d++) {
              int row = d * 32 + q31;
              int vsw = (row & 7) << 4;
              s16x8 vf = *(const s16x8*)(VsB + row * 128 + ((kc * 32 + hh * 16) ^ vsw));
              o[d] = __builtin_amdgcn_mfma_f32_32x32x16_bf16(vf, pf, o[d], 0, 0, 0);
            }
            __builtin_amdgcn_s_setprio(0);
          }
        }
      }
      cur ^= 1;
    }
    float linv = 1.0f / l;
    u16* Op = Oact + (size_t)(b * S_LEN + qw0 + q31) * 4096 + h * HD;
#pragma unroll
    for (int d = 0; d < 4; d++)
#pragma unroll
      for (int g4 = 0; g4 < 4; g4++) {
        int d0 = d * 32 + 8 * g4 + 4 * hh;
        u16x4 w4 = {f2bf(o[d][4 * g4 + 0] * linv), f2bf(o[d][4 * g4 + 1] * linv),
                    f2bf(o[d][4 * g4 + 2] * linv), f2bf(o[d][4 * g4 + 3] * linv)};
        *(u16x4*)(Op + d0) = w4;
      }
  }
}

extern "C" void kernel_launch(void* const* d_in, const int* in_sizes, int n_in,
                              void* d_out, int out_size, void* d_ws,
                              size_t ws_size, hipStream_t stream) {
  (void)in_sizes; (void)n_in; (void)out_size; (void)ws_size;
  const float* X = (const float*)d_in[0];
  const int* pos = (const int*)d_in[1];
  const float* Wq = (const float*)d_in[2];
  const float* Wk = (const float*)d_in[3];
  const float* Wv = (const float*)d_in[4];
  const float* Wo = (const float*)d_in[5];
  const float* qw = (const float*)d_in[6];
  const float* kw = (const float*)d_in[7];
  float* out = (float*)d_out;
  char* ws = (char*)d_ws;

  const size_t MB = 1024ull * 1024ull;
  u16* Xb    = (u16*)(ws + 0 * MB);     // [4096][4096] bf16     32 MiB
  u16* WqkvT = (u16*)(ws + 32 * MB);    // [6144][4096] fused    48 MiB
  u16* WkvT  = (u16*)(ws + 64 * MB);    //   (rows 4096..6143 of WqkvT)
  u16* WoT   = (u16*)(ws + 80 * MB);    // [4096][4096]          32 MiB
  u16* QKV   = (u16*)(ws + 112 * MB);   // [4096][6144]          48 MiB
  u16* Vt    = (u16*)(ws + 160 * MB);   // [16*128][2048]         8 MiB
  u16* Oact  = (u16*)(ws + 168 * MB);   // [4096][4096]          32 MiB
  float* tab = (float*)(ws + 200 * MB); // [2048][128]            1 MiB

  k_convert<<<8192, 256, 0, stream>>>(X, Xb, (T_TOK * HIDDEN) / 8);
  k_transpose_w<<<dim3(128, 128), 256, 0, stream>>>(Wq, WqkvT, 4096, 4096, 0, 4096);
  k_transpose_w<<<dim3(128, 32), 256, 0, stream>>>(Wk, WkvT, 4096, 1024, 0, 4096);
  k_transpose_w<<<dim3(128, 32), 256, 0, stream>>>(Wv, WkvT, 4096, 1024, 1024, 4096);
  k_transpose_w<<<dim3(128, 128), 256, 0, stream>>>(Wo, WoT, 4096, 4096, 0, 4096);
  k_rope_tab<<<512, 256, 0, stream>>>(pos, tab);

  // fused QKV projection: [4096][4096] x [6144][4096]^T -> [4096][6144]
  k_gemm8p<u16><<<16 * 24, 512, 0, stream>>>(Xb, WqkvT, QKV, QKV_W, 4096);

  k_rmsrope<<<(T_TOK * NHEADS) / 4, 256, 0, stream>>>(QKV, qw, tab, NHEADS, QKV_W);
  k_rmsrope<<<(T_TOK * NKV) / 4, 256, 0, stream>>>(QKV + 4096, kw, tab, NKV, QKV_W);

  k_transpose_v<<<dim3(16, 64, 4), 256, 0, stream>>>(QKV, Vt);

  k_attn<<<512, 256, 0, stream>>>(QKV, Vt, Oact);

  k_gemm8p<float><<<16 * 16, 512, 0, stream>>>(Oact, WoT, out, 4096, 4096);
}

// Round 16
// 630.949 us; speedup vs baseline: 1.0763x; 1.0763x over previous
//
#include <hip/hip_runtime.h>
#include <stdint.h>
#include <stddef.h>

#define S_LEN 2048
#define BATCH 2
#define NHEADS 32
#define NKV 8
#define HD 128
#define HIDDEN 4096
#define T_TOK (BATCH * S_LEN)
// fused QKV activation row: [0,4096)=Q heads, [4096,5120)=K, [5120,6144)=V
#define QKV_W 6144

typedef unsigned short u16;
typedef __attribute__((ext_vector_type(4))) float f32x4;
typedef __attribute__((ext_vector_type(16))) float f32x16;
typedef __attribute__((ext_vector_type(8))) short s16x8;
typedef __attribute__((ext_vector_type(4))) unsigned short u16x4;
typedef __attribute__((ext_vector_type(4))) unsigned int u32x4;

__device__ __forceinline__ u16 f2bf(float f) {
  unsigned int u = __builtin_bit_cast(unsigned int, f);
  unsigned int r = (u + 0x7FFFu + ((u >> 16) & 1u)) >> 16;
  return (u16)r;
}
__device__ __forceinline__ float bf2f(u16 h) {
  return __builtin_bit_cast(float, ((unsigned int)h) << 16);
}

__device__ __forceinline__ void gload16(const void* g, void* l) {
  __builtin_amdgcn_global_load_lds((__attribute__((address_space(1))) void*)g,
                                   (__attribute__((address_space(3))) void*)l,
                                   16, 0, 0);
}

__device__ __forceinline__ unsigned cvtpk(float a, float b) {
  unsigned r;
  asm("v_cvt_pk_bf16_f32 %0, %1, %2" : "=v"(r) : "v"(a), "v"(b));
  return r;
}
__device__ __forceinline__ void lohi_dup(unsigned W, unsigned& lo, unsigned& hi) {
  unsigned a = W, b = W;
  asm volatile("v_permlane32_swap_b32 %0, %1" : "+v"(a), "+v"(b));
  lo = a; hi = b;
}

// ---------------- convert f32 -> bf16 (8 elems / thread) ----------------
__global__ __launch_bounds__(256) void k_convert(const float* __restrict__ in,
                                                 u16* __restrict__ out, int n8) {
  int i = blockIdx.x * 256 + threadIdx.x;
  if (i >= n8) return;
  float4 a = ((const float4*)in)[i * 2];
  float4 b = ((const float4*)in)[i * 2 + 1];
  u16x4 lo = {f2bf(a.x), f2bf(a.y), f2bf(a.z), f2bf(a.w)};
  u16x4 hi = {f2bf(b.x), f2bf(b.y), f2bf(b.z), f2bf(b.w)};
  ((u16x4*)out)[i * 2] = lo;
  ((u16x4*)out)[i * 2 + 1] = hi;
}

// ------------- transpose-convert W [K][N] f32 -> Wt [N][K] bf16 ----------
__global__ __launch_bounds__(256) void k_transpose_w(const float* __restrict__ W,
                                                     u16* __restrict__ Wt, int K,
                                                     int N, int outRowOff,
                                                     int outStride) {
  __shared__ float tl[32][33];
  int k0 = blockIdx.x * 32, n0 = blockIdx.y * 32;
  int t = threadIdx.x;
  int r = t >> 3, c4 = (t & 7) * 4;
  float4 v = *(const float4*)&W[(size_t)(k0 + r) * N + n0 + c4];
  tl[r][c4] = v.x; tl[r][c4 + 1] = v.y; tl[r][c4 + 2] = v.z; tl[r][c4 + 3] = v.w;
  __syncthreads();
  u16x4 o = {f2bf(tl[c4][r]), f2bf(tl[c4 + 1][r]), f2bf(tl[c4 + 2][r]),
             f2bf(tl[c4 + 3][r])};
  *(u16x4*)&Wt[(size_t)(outRowOff + n0 + r) * outStride + k0 + c4] = o;
}

// ---------------- RoPE cos/sin table: tab[s][0:64]=cos, [64:128]=sin -----
__global__ __launch_bounds__(256) void k_rope_tab(const int* __restrict__ pos,
                                                  float* __restrict__ tab) {
  int i = blockIdx.x * 256 + threadIdx.x;  // S*64
  int s = i >> 6, l = i & 63;
  float p = (float)pos[s];
  float ang = p * expf(-(float)l * 0.14391156516342163f);
  tab[s * 128 + l] = cosf(ang);
  tab[s * 128 + 64 + l] = sinf(ang);
}

// ===== 256x256xBK64 8-wave 8-PHASE GEMM, ONE barrier per phase ============
// Session-best GEMM (R14, verified 247us QKV / MfmaUtil 35%). Phase =
// {ds-read frags, stage half-tile, lgkm0+sched0, 16 MFMA, [vmcnt], barrier}.
// SAFETY: (1) intra-phase stage targets disjoint from same-phase reads
// (different array or buffer, all 8 phases checked); (2) cross-phase: a
// wave's phase-p ds_reads retire at its lgkm0 BEFORE it passes p's trailing
// barrier; p+1 stages issue after -> no WAR. VMCNT: end-p3 VM(4) (newest 4 =
// p2,p3 stages -> tile 2j+1 landed); final iter VM(0) (counted wait would
// no-op, R8 bug class); end-p7 VM(4) (tile 2j+2 landed). Every VM is
// followed by s_barrier. NOTE (R15 lesson): do NOT add register prefetch --
// +96 VGPR of fragments spills to scratch (WRITE_SIZE 49->150 MB, -9%).
template <typename OutT>
__global__ __launch_bounds__(512, 2) void k_gemm8p(const u16* __restrict__ A,
                                                   const u16* __restrict__ Bt,
                                                   OutT* __restrict__ C,
                                                   int N, int K) {
  __shared__ u16 As[2][16384];  // [buf][256 rows][64 k], xor-swizzled rows
  __shared__ u16 Bs[2][16384];
  int nbn = N >> 8;
  int nwg = gridDim.x;
  int orig = blockIdx.x;
  int q8 = nwg >> 3, r8 = nwg & 7;
  int xcd = orig & 7, sub = orig >> 3;
  int wgid = (xcd < r8 ? xcd * (q8 + 1) : r8 * (q8 + 1) + (xcd - r8) * q8) + sub;
  int bm = wgid / nbn, bn = wgid % nbn;
  int tid = threadIdx.x, wid = tid >> 6, lane = tid & 63;
  int wm = wid >> 2, wn = wid & 3;  // 2M x 4N waves; wave tile 128x64
  int g = lane >> 4, c = lane & 15;
  int l3 = lane >> 3, l7 = lane & 7;
  int swz = c & 7;
  int xunit = (l7 ^ l3) * 8;  // inverse-swizzled 16B unit for staging

  f32x4 acc[8][4];
#pragma unroll
  for (int m = 0; m < 8; m++)
#pragma unroll
    for (int n = 0; n < 4; n++) acc[m][n] = (f32x4){0.f, 0.f, 0.f, 0.f};

  const u16* aBase = A + (size_t)(bm * 256 + wid * 16 + l3) * K + xunit;
  const u16* bBase = Bt + (size_t)(bn * 256 + wid * 16 + l3) * K + xunit;

  // stage one 128-row half-tile: 2 gload16 per thread (16 instrs per block)
  auto stgA = [&](int buf, int h, size_t koff) {
    gload16(aBase + (size_t)(h * 128) * K + koff,
            &As[buf][(h * 128 + wid * 16) * 64]);
    gload16(aBase + (size_t)(h * 128 + 8) * K + koff,
            &As[buf][(h * 128 + wid * 16 + 8) * 64]);
  };
  auto stgB = [&](int buf, int h, size_t koff) {
    gload16(bBase + (size_t)(h * 128) * K + koff,
            &Bs[buf][(h * 128 + wid * 16) * 64]);
    gload16(bBase + (size_t)(h * 128 + 8) * K + koff,
            &Bs[buf][(h * 128 + wid * 16 + 8) * 64]);
  };

  s16x8 af[4][2], bf0[2][2], bf1[2][2];
  auto rdA = [&](int buf, int mh) {
#pragma unroll
    for (int mi = 0; mi < 4; mi++)
#pragma unroll
      for (int ks = 0; ks < 2; ks++)
        af[mi][ks] = *(const s16x8*)&As[buf][(wm * 128 + mh * 64 + mi * 16 + c) * 64 +
                                            (((ks * 4 + g) ^ swz) * 8)];
  };
  auto rdB = [&](int buf, int nh, s16x8 (&bf)[2][2]) {
#pragma unroll
    for (int nj = 0; nj < 2; nj++)
#pragma unroll
      for (int ks = 0; ks < 2; ks++)
        bf[nj][ks] = *(const s16x8*)&Bs[buf][(wn * 64 + nh * 32 + nj * 16 + c) * 64 +
                                            (((ks * 4 + g) ^ swz) * 8)];
  };
  auto quad = [&](int mh, int nh, s16x8 (&bf)[2][2]) {
    __builtin_amdgcn_s_setprio(1);
#pragma unroll
    for (int mi = 0; mi < 4; mi++)
#pragma unroll
      for (int nj = 0; nj < 2; nj++)
#pragma unroll
        for (int ks = 0; ks < 2; ks++)
          acc[mh * 4 + mi][nh * 2 + nj] = __builtin_amdgcn_mfma_f32_16x16x32_bf16(
              af[mi][ks], bf[nj][ks], acc[mh * 4 + mi][nh * 2 + nj], 0, 0, 0);
    __builtin_amdgcn_s_setprio(0);
  };
#define BAR() __builtin_amdgcn_s_barrier()
#define LGKM0()                                     \
  do {                                              \
    asm volatile("s_waitcnt lgkmcnt(0)" ::: "memory"); \
    __builtin_amdgcn_sched_barrier(0);              \
  } while (0)
#define VM(n) asm volatile("s_waitcnt vmcnt(" #n ")" ::: "memory")

  int nt2 = K >> 7;  // iterations; 2 K-tiles each (K=4096 -> 32)
  // prologue: t0 -> buf0 (B0,B1,A0,A1), t1.B -> buf1. 12 ops; vmcnt(4)
  // leaves only t1.B outstanding -> t0 complete.
  stgB(0, 0, 0); stgB(0, 1, 0);
  stgA(0, 0, 0); stgA(0, 1, 0);
  stgB(1, 0, 64); stgB(1, 1, 64);
  VM(4);
  BAR();

  for (int j = 0; j < nt2; j++) {
    size_t k1 = (size_t)(2 * j + 1) << 6;
    size_t k2 = (size_t)(2 * j + 2) << 6;
    size_t k3 = (size_t)(2 * j + 3) << 6;
    bool st = (j + 1 < nt2);  // stage tiles 2j+2, 2j+3?
    // ---- P0: tile 2j (buf0) Q(mh0,nh0); stage (2j+1).A0 -> buf1 ----
    rdA(0, 0); rdB(0, 0, bf0);
    stgA(1, 0, k1);
    LGKM0();
    quad(0, 0, bf0);
    BAR();
    // ---- P1: Q(mh0,nh1); stage (2j+1).A1 -> buf1 ----
    rdB(0, 1, bf1);
    stgA(1, 1, k1);
    LGKM0();
    quad(0, 1, bf1);
    BAR();
    // ---- P2: Q(mh1,nh0); stage (2j+2).B0 -> buf0 ----
    rdA(0, 1);
    if (st) stgB(0, 0, k2);
    LGKM0();
    quad(1, 0, bf0);
    BAR();
    // ---- P3: Q(mh1,nh1); stage (2j+2).B1 -> buf0; WAIT(tile 2j+1) ----
    if (st) stgB(0, 1, k2);
    LGKM0();
    quad(1, 1, bf1);
    if (st) { VM(4); } else { VM(0); }
    BAR();
    // ---- P4: tile 2j+1 (buf1) Q(mh0,nh0); stage (2j+2).A0 -> buf0 ----
    rdA(1, 0); rdB(1, 0, bf0);
    if (st) stgA(0, 0, k2);
    LGKM0();
    quad(0, 0, bf0);
    BAR();
    // ---- P5: Q(mh0,nh1); stage (2j+2).A1 -> buf0 ----
    rdB(1, 1, bf1);
    if (st) stgA(0, 1, k2);
    LGKM0();
    quad(0, 1, bf1);
    BAR();
    // ---- P6: Q(mh1,nh0); stage (2j+3).B0 -> buf1 ----
    rdA(1, 1);
    if (st) stgB(1, 0, k3);
    LGKM0();
    quad(1, 0, bf0);
    BAR();
    // ---- P7: Q(mh1,nh1); stage (2j+3).B1 -> buf1; WAIT(tile 2j+2) ----
    if (st) stgB(1, 1, k3);
    LGKM0();
    quad(1, 1, bf1);
    if (st) { VM(4); }
    BAR();
  }
#undef BAR
#undef LGKM0
#undef VM

  // epilogue
#pragma unroll
  for (int m = 0; m < 8; m++)
#pragma unroll
    for (int n = 0; n < 4; n++) {
      size_t row = (size_t)bm * 256 + wm * 128 + m * 16 + g * 4;
      size_t col = (size_t)bn * 256 + wn * 64 + n * 16 + c;
#pragma unroll
      for (int r = 0; r < 4; r++) {
        float v = acc[m][n][r];
        if constexpr (sizeof(OutT) == 2)
          C[(row + r) * N + col] = (OutT)f2bf(v);
        else
          C[(row + r) * N + col] = (OutT)v;
      }
    }
}

// ------------- fused per-head RMSNorm + RoPE (in-place, bf16) ------------
__global__ __launch_bounds__(256) void k_rmsrope(u16* __restrict__ QK,
                                                 const float* __restrict__ w,
                                                 const float* __restrict__ tab,
                                                 int H, int rowStride) {
  int row = blockIdx.x * 4 + (threadIdx.x >> 6);
  int lane = threadIdx.x & 63;
  int t = row / H, h = row - t * H;
  int s = t & (S_LEN - 1);
  u16* p = QK + (size_t)t * rowStride + h * HD;
  float x1 = bf2f(p[lane]), x2 = bf2f(p[lane + 64]);
  float ss = x1 * x1 + x2 * x2;
#pragma unroll
  for (int o = 32; o >= 1; o >>= 1) ss += __shfl_xor(ss, o);
  float inv = rsqrtf(ss * (1.0f / 128.0f) + 1e-6f);
  float y1 = x1 * inv * w[lane], y2 = x2 * inv * w[lane + 64];
  float cs = tab[s * 128 + lane], sn = tab[s * 128 + 64 + lane];
  p[lane] = f2bf(y1 * cs - y2 * sn);
  p[lane + 64] = f2bf(y2 * cs + y1 * sn);
}

// ---- transpose V: QKV[t][5120 + kh*128 + d] -> Vt[bkh*128+d][s] ----
__global__ __launch_bounds__(256) void k_transpose_v(const u16* __restrict__ QKV,
                                                     u16* __restrict__ Vt) {
  __shared__ u16 tl[32][40];
  int bkh = blockIdx.x;
  int s0 = blockIdx.y * 32, d0 = blockIdx.z * 32;
  int b = bkh >> 3, kh = bkh & 7;
  int t = threadIdx.x, r = t >> 3, c4 = (t & 7) * 4;
  const u16* src =
      QKV + (size_t)(b * S_LEN + s0 + r) * QKV_W + 5120 + kh * HD + d0 + c4;
  u16x4 v = *(const u16x4*)src;
  tl[r][c4] = v[0]; tl[r][c4 + 1] = v[1]; tl[r][c4 + 2] = v[2]; tl[r][c4 + 3] = v[3];
  __syncthreads();
  u16x4 o = {tl[c4][r], tl[c4 + 1][r], tl[c4 + 2][r], tl[c4 + 3][r]};
  *(u16x4*)&Vt[(size_t)(bkh * HD + d0 + r) * S_LEN + s0 + c4] = o;
}

// --------------------------- causal GQA attention ------------------------
// R7/R11-PROVEN structure (do not touch sync): 512 blocks, XCD-grouped;
// each block = one (b,h) processing q-tile PAIR {p, 15-p}; K,V double-
// buffered in 64 KiB LDS; ONE __syncthreads per chunk. Log2-domain softmax,
// T12 repack, T13 defer-max, T5 setprio.
__global__ __launch_bounds__(256) void k_attn(const u16* __restrict__ QKV,
                                              const u16* __restrict__ Vt,
                                              u16* __restrict__ Oact) {
  __shared__ u16 Ks[2][64 * 128];
  __shared__ u16 Vs[2][128 * 64];
  int bid = blockIdx.x;
  int xcd = bid & 7, slot = bid >> 3;
  int grp = xcd * 2 + (slot >> 5);  // 16 groups = b*8 + kh
  int b = grp >> 3, kh = grp & 7;
  int s32 = slot & 31;
  int pr = s32 >> 2;
  int h = kh * 4 + (s32 & 3);
  int w = threadIdx.x >> 6, lane = threadIdx.x & 63;
  int q31 = lane & 31, hh = lane >> 5;
  const float qscale = 0.12751740810f;  // 1/sqrt(128) * log2(e)

  const char* Kg = (const char*)(QKV + (size_t)b * S_LEN * QKV_W + 4096 + kh * HD);
  const char* Vg = (const char*)(Vt + (size_t)(b * 8 + kh) * HD * S_LEN);

#pragma unroll 1
  for (int half = 0; half < 2; half++) {
    __syncthreads();  // half-boundary safety: all prior LDS reads retired
    int qt = half ? 15 - pr : pr;
    int qw0 = qt * 128 + w * 32;

    s16x8 qf[8];
    const u16* Qp = QKV + (size_t)(b * S_LEN + qw0 + q31) * QKV_W + h * HD + hh * 8;
#pragma unroll
    for (int dc = 0; dc < 8; dc++) {
      s16x8 raw = *(const s16x8*)(Qp + dc * 16);
#pragma unroll
      for (int e = 0; e < 8; e++)
        qf[dc][e] = (short)f2bf(bf2f((u16)raw[e]) * qscale);
    }

    f32x16 o[4];
#pragma unroll
    for (int d = 0; d < 4; d++)
#pragma unroll
      for (int r = 0; r < 16; r++) o[d][r] = 0.f;
    float m = -3.0e38f, l = 0.f;

    int nch = 2 * qt + 2;

    {
      char* KsB = (char*)Ks[0];
      char* VsB = (char*)Vs[0];
#pragma unroll
      for (int j = 0; j < 4; j++) {
        int ins = w * 4 + j;
        int row = ins * 4 + (lane >> 4);
        int bc = ((lane & 15) * 16) ^ ((row & 7) << 4);
        gload16(Kg + (size_t)row * 12288 + bc, KsB + ins * 1024);
      }
#pragma unroll
      for (int j = 0; j < 4; j++) {
        int ins = w * 4 + j;
        int row = ins * 8 + (lane >> 3);
        int bc = ((lane & 7) * 16) ^ ((row & 7) << 4);
        gload16(Vg + (size_t)row * 4096 + bc, VsB + ins * 1024);
      }
    }

    int cur = 0;
    for (int ch = 0; ch < nch; ch++) {
      int kb = ch * 64;
      __syncthreads();
      if (ch + 1 < nch) {
        char* KsB = (char*)Ks[cur ^ 1];
        char* VsB = (char*)Vs[cur ^ 1];
        int kb2 = kb + 64;
#pragma unroll
        for (int j = 0; j < 4; j++) {
          int ins = w * 4 + j;
          int row = ins * 4 + (lane >> 4);
          int bc = ((lane & 15) * 16) ^ ((row & 7) << 4);
          gload16(Kg + (size_t)(kb2 + row) * 12288 + bc, KsB + ins * 1024);
        }
#pragma unroll
        for (int j = 0; j < 4; j++) {
          int ins = w * 4 + j;
          int row = ins * 8 + (lane >> 3);
          int bc = ((lane & 7) * 16) ^ ((row & 7) << 4);
          gload16(Vg + (size_t)row * 4096 + (size_t)kb2 * 2 + bc, VsB + ins * 1024);
        }
      }
      if (kb <= qw0 + 31) {
        char* KsB = (char*)Ks[cur];
        char* VsB = (char*)Vs[cur];
        f32x16 sA, sB;
#pragma unroll
        for (int r = 0; r < 16; r++) { sA[r] = 0.f; sB[r] = 0.f; }
        int sw = (q31 & 7) << 4;
        __builtin_amdgcn_s_setprio(1);
#pragma unroll
        for (int dc = 0; dc < 8; dc++) {
          s16x8 kfA = *(const s16x8*)(KsB + q31 * 256 + ((dc * 32 + hh * 16) ^ sw));
          s16x8 kfB = *(const s16x8*)(KsB + (32 + q31) * 256 + ((dc * 32 + hh * 16) ^ sw));
          sA = __builtin_amdgcn_mfma_f32_32x32x16_bf16(kfA, qf[dc], sA, 0, 0, 0);
          sB = __builtin_amdgcn_mfma_f32_32x32x16_bf16(kfB, qf[dc], sB, 0, 0, 0);
        }
        __builtin_amdgcn_s_setprio(0);
        if (kb + 63 > qw0) {
          int qa = qw0 + q31;
#pragma unroll
          for (int r = 0; r < 16; r++) {
            int krow = (r & 3) + 8 * (r >> 2) + 4 * hh;
            if (kb + krow > qa) sA[r] = -1e30f;
            if (kb + 32 + krow > qa) sB[r] = -1e30f;
          }
        }
        float mx = -3.0e38f;
#pragma unroll
        for (int r = 0; r < 16; r++) mx = fmaxf(mx, fmaxf(sA[r], sB[r]));
        mx = fmaxf(mx, __shfl_xor(mx, 32));
        if (!__all(mx - m <= 11.5f)) {
          float mnew = fmaxf(m, mx);
          float corr = __builtin_amdgcn_exp2f(m - mnew);
          l *= corr;
#pragma unroll
          for (int d = 0; d < 4; d++)
#pragma unroll
            for (int r = 0; r < 16; r++) o[d][r] *= corr;
          m = mnew;
        }
        float rs = 0.f;
#pragma unroll
        for (int r = 0; r < 16; r++) {
          sA[r] = __builtin_amdgcn_exp2f(sA[r] - m); rs += sA[r];
          sB[r] = __builtin_amdgcn_exp2f(sB[r] - m); rs += sB[r];
        }
        rs += __shfl_xor(rs, 32);
        l += rs;
#pragma unroll
        for (int st = 0; st < 2; st++) {
          unsigned Aw[8], Bw[8];
#pragma unroll
          for (int j = 0; j < 8; j++) {
            float p0 = st ? sB[2 * j] : sA[2 * j];
            float p1 = st ? sB[2 * j + 1] : sA[2 * j + 1];
            lohi_dup(cvtpk(p0, p1), Aw[j], Bw[j]);
          }
#pragma unroll
          for (int kc2 = 0; kc2 < 2; kc2++) {
            u32x4 wv;
            wv.x = hh ? Aw[kc2 * 4 + 2] : Aw[kc2 * 4 + 0];
            wv.y = hh ? Aw[kc2 * 4 + 3] : Aw[kc2 * 4 + 1];
            wv.z = hh ? Bw[kc2 * 4 + 2] : Bw[kc2 * 4 + 0];
            wv.w = hh ? Bw[kc2 * 4 + 3] : Bw[kc2 * 4 + 1];
            s16x8 pf = __builtin_bit_cast(s16x8, wv);
            int kc = st * 2 + kc2;
            __builtin_amdgcn_s_setprio(1);
#pragma unroll
            for (int d = 0; d < 4; d++) {
              int row = d * 32 + q31;
              int vsw = (row & 7) << 4;
              s16x8 vf = *(const s16x8*)(VsB + row * 128 + ((kc * 32 + hh * 16) ^ vsw));
              o[d] = __builtin_amdgcn_mfma_f32_32x32x16_bf16(vf, pf, o[d], 0, 0, 0);
            }
            __builtin_amdgcn_s_setprio(0);
          }
        }
      }
      cur ^= 1;
    }
    float linv = 1.0f / l;
    u16* Op = Oact + (size_t)(b * S_LEN + qw0 + q31) * 4096 + h * HD;
#pragma unroll
    for (int d = 0; d < 4; d++)
#pragma unroll
      for (int g4 = 0; g4 < 4; g4++) {
        int d0 = d * 32 + 8 * g4 + 4 * hh;
        u16x4 w4 = {f2bf(o[d][4 * g4 + 0] * linv), f2bf(o[d][4 * g4 + 1] * linv),
                    f2bf(o[d][4 * g4 + 2] * linv), f2bf(o[d][4 * g4 + 3] * linv)};
        *(u16x4*)(Op + d0) = w4;
      }
  }
}

extern "C" void kernel_launch(void* const* d_in, const int* in_sizes, int n_in,
                              void* d_out, int out_size, void* d_ws,
                              size_t ws_size, hipStream_t stream) {
  (void)in_sizes; (void)n_in; (void)out_size; (void)ws_size;
  const float* X = (const float*)d_in[0];
  const int* pos = (const int*)d_in[1];
  const float* Wq = (const float*)d_in[2];
  const float* Wk = (const float*)d_in[3];
  const float* Wv = (const float*)d_in[4];
  const float* Wo = (const float*)d_in[5];
  const float* qw = (const float*)d_in[6];
  const float* kw = (const float*)d_in[7];
  float* out = (float*)d_out;
  char* ws = (char*)d_ws;

  const size_t MB = 1024ull * 1024ull;
  u16* Xb    = (u16*)(ws + 0 * MB);     // [4096][4096] bf16     32 MiB
  u16* WqkvT = (u16*)(ws + 32 * MB);    // [6144][4096] fused    48 MiB
  u16* WkvT  = (u16*)(ws + 64 * MB);    //   (rows 4096..6143 of WqkvT)
  u16* WoT   = (u16*)(ws + 80 * MB);    // [4096][4096]          32 MiB
  u16* QKV   = (u16*)(ws + 112 * MB);   // [4096][6144]          48 MiB
  u16* Vt    = (u16*)(ws + 160 * MB);   // [16*128][2048]         8 MiB
  u16* Oact  = (u16*)(ws + 168 * MB);   // [4096][4096]          32 MiB
  float* tab = (float*)(ws + 200 * MB); // [2048][128]            1 MiB

  k_convert<<<8192, 256, 0, stream>>>(X, Xb, (T_TOK * HIDDEN) / 8);
  k_transpose_w<<<dim3(128, 128), 256, 0, stream>>>(Wq, WqkvT, 4096, 4096, 0, 4096);
  k_transpose_w<<<dim3(128, 32), 256, 0, stream>>>(Wk, WkvT, 4096, 1024, 0, 4096);
  k_transpose_w<<<dim3(128, 32), 256, 0, stream>>>(Wv, WkvT, 4096, 1024, 1024, 4096);
  k_transpose_w<<<dim3(128, 128), 256, 0, stream>>>(Wo, WoT, 4096, 4096, 0, 4096);
  k_rope_tab<<<512, 256, 0, stream>>>(pos, tab);

  // fused QKV projection: [4096][4096] x [6144][4096]^T -> [4096][6144]
  k_gemm8p<u16><<<16 * 24, 512, 0, stream>>>(Xb, WqkvT, QKV, QKV_W, 4096);

  k_rmsrope<<<(T_TOK * NHEADS) / 4, 256, 0, stream>>>(QKV, qw, tab, NHEADS, QKV_W);
  k_rmsrope<<<(T_TOK * NKV) / 4, 256, 0, stream>>>(QKV + 4096, kw, tab, NKV, QKV_W);

  k_transpose_v<<<dim3(16, 64, 4), 256, 0, stream>>>(QKV, Vt);

  k_attn<<<512, 256, 0, stream>>>(QKV, Vt, Oact);

  k_gemm8p<float><<<16 * 16, 512, 0, stream>>>(Oact, WoT, out, 4096, 4096);
}